// Round 3
// baseline (133.811 us; speedup 1.0000x reference)
//
#include <hip/hip_runtime.h>

// MultiLIF forward: B=32, L=2048, K=512. One thread per (b,k); 256 waves total
// (1 wave/CU, structural). Exact-numerics constraints: IEEE-div replaced by
// provably-identical f64-multiply rounding; no fma contraction; spike select
// and reset are exact.
//
// R3 change: store widening. Writes (268 MB, all HBM) were issued as 2x
// global_store_dword (256B) per step; per-wave outstanding-store entries cap
// write BW at ~1.65 TB/s. Transpose 4 steps x 64 lanes through LDS
// (wave-synchronous, no __syncthreads -> no vmcnt(0) drain) so each lane
// stores a float4 covering 4 k's of one t: 4x fewer store instructions,
// 4x bytes per outstanding entry.

#define LL 2048
#define KK 512

typedef float f4v __attribute__((ext_vector_type(4)));
typedef float f2v __attribute__((ext_vector_type(2)));

constexpr int U = 8;   // steps per sub-block
constexpr int NB = 4;  // rotating register prefetch buffers (distance 24-32 steps)

__global__ __launch_bounds__(64, 1) void lif_kernel(const float* __restrict__ I,
                                                    float* __restrict__ spikes,
                                                    float* __restrict__ series) {
#pragma clang fp contract(off)
    const int lane = threadIdx.x;
    const int e0 = blockIdx.x * 64;          // first element of this wave
    const int b = e0 >> 9;
    const int k0 = e0 & 511;
    const size_t bbase = (size_t)b * LL * KK;
    const float* Ip = I + bbase + k0 + lane; // per-lane load stream
    float* spb = spikes + bbase + k0;        // wave-base for transposed stores
    float* ssb = series + bbase + k0;

    // [phase][t&3][k-lane][s|n] : 4 KB. Two phases so group-B writes never
    // collide with pending group-A flush reads.
    __shared__ __align__(16) float l2[2][4][64][2];

    const int tr = lane >> 4;        // time-row this lane stores (0..3)
    const int kq = (lane & 15) * 4;  // k-quad this lane stores (0..60)

    float v = 0.0f, a = 0.0f, n = 0.0f;

    float q[NB][U];  // all indices compile-time after unrolling
#pragma unroll
    for (int st = 0; st < NB; ++st)
#pragma unroll
        for (int u = 0; u < U; ++u)
            q[st][u] = Ip[(size_t)(st * U + u) * KK];

    for (int t0 = 0; t0 < LL; t0 += NB * U) {
#pragma unroll
        for (int st = 0; st < NB; ++st) {
            const int tb = t0 + st * U;
#pragma unroll
            for (int u = 0; u < U; ++u) {
                const float It = q[st][u];
                // v = (v - v/TAU) + I_t ; v/20 via exact f64-mul rounding
                v = v - (float)((double)v * 0.05) + It;
                const float th = 1.0f + 1.5f * a;   // mul then add, no fma
                const bool fired = (v >= th);
                const float s1 = fired ? 1.0f : 0.0f;
                n = n + s1;                         // cumulative count (exact)
                v = fired ? -0.5f : v;              // exact select
                a = a - (float)((double)a * 0.01) + s1;

                const int ph = u >> 2;
                *(f2v*)&l2[ph][u & 3][lane][0] = f2v{s1, n};  // ds_write_b64

                if ((u & 3) == 3) {
                    // flush group: lane -> (t = tb + ph*4 + tr, k = kq..kq+3)
                    const f4v A = *(const f4v*)&l2[ph][tr][kq][0];
                    const f4v B = *(const f4v*)&l2[ph][tr][kq + 2][0];
                    const f4v vs = {A.x, A.z, B.x, B.z};
                    const f4v vn = {A.y, A.w, B.y, B.w};
                    const size_t to = (size_t)(tb + ph * 4 + tr) * KK + kq;
                    __builtin_nontemporal_store(vs, (f4v*)(spb + to));
                    __builtin_nontemporal_store(vn, (f4v*)(ssb + to));
                }
            }
            // prefetch the sub-block NB*U steps ahead into the buffer just freed
            if (tb + NB * U < LL) {
#pragma unroll
                for (int u = 0; u < U; ++u)
                    q[st][u] = Ip[(size_t)(tb + NB * U + u) * KK];
            }
        }
    }
}

extern "C" void kernel_launch(void* const* d_in, const int* in_sizes, int n_in,
                              void* d_out, int out_size, void* d_ws, size_t ws_size,
                              hipStream_t stream) {
    const float* I = (const float*)d_in[0];
    float* spikes = (float*)d_out;
    float* series = (float*)d_out + (size_t)32 * LL * KK;
    lif_kernel<<<256, 64, 0, stream>>>(I, spikes, series);
}